// Round 6
// baseline (3837.905 us; speedup 1.0000x reference)
//
#include <hip/hip_runtime.h>

// MoE switch layer: B=8, N=2048, D=1024, E=8, DFF=4096, CAP=320
#define Bq 8
#define Nq 2048
#define Dq 1024
#define Eq 8
#define DFFq 4096
#define CAPq 320
#define Mq (Bq * CAPq)   // 2560 rows per expert
#define Tq (Bq * Nq)     // 16384 tokens

typedef __attribute__((ext_vector_type(8))) short bf16x8;
typedef __attribute__((ext_vector_type(4))) float f32x4;

static __device__ __forceinline__ unsigned short f2bf(float f) {
    union { float f; unsigned u; } v;
    v.f = f;
    unsigned r = v.u + 0x7fffu + ((v.u >> 16) & 1u);   // RNE
    return (unsigned short)(r >> 16);
}

static __device__ __forceinline__ void gload_lds16(const void* g, void* l) {
    __builtin_amdgcn_global_load_lds(
        (const __attribute__((address_space(1))) unsigned int*)g,
        (__attribute__((address_space(3))) unsigned int*)l, 16, 0, 0);
}

// ---------------- routing: logits -> softmax -> argmax/gate ----------------
__global__ __launch_bounds__(256) void route_kernel(
    const float* __restrict__ tok, const float* __restrict__ Wg,
    int* __restrict__ eidx, float* __restrict__ gate)
{
    int wv = threadIdx.x >> 6, lane = threadIdx.x & 63;
    int t = blockIdx.x * 4 + wv;
    const float* tp = tok + (size_t)t * Dq;
    float acc[8] = {0.f,0.f,0.f,0.f,0.f,0.f,0.f,0.f};
    for (int it = 0; it < Dq / 64; ++it) {
        int d = it * 64 + lane;
        float x = tp[d];
        const float4* w = (const float4*)(Wg + (size_t)d * 8);
        float4 w0 = w[0], w1 = w[1];
        acc[0] += x * w0.x; acc[1] += x * w0.y; acc[2] += x * w0.z; acc[3] += x * w0.w;
        acc[4] += x * w1.x; acc[5] += x * w1.y; acc[6] += x * w1.z; acc[7] += x * w1.w;
    }
#pragma unroll
    for (int e = 0; e < 8; ++e)
#pragma unroll
        for (int off = 32; off; off >>= 1)
            acc[e] += __shfl_xor(acc[e], off, 64);
    if (lane == 0) {
        float m = acc[0]; int bi = 0;
#pragma unroll
        for (int e = 1; e < 8; ++e) if (acc[e] > m) { m = acc[e]; bi = e; }
        float s = 0.f;
#pragma unroll
        for (int e = 0; e < 8; ++e) s += expf(acc[e] - m);
        eidx[t] = bi;
        gate[t] = 1.0f / s;   // max prob
    }
}

// ------------- slot assignment + zero dropped-token output rows ------------
__global__ __launch_bounds__(64) void slot_kernel(
    const int* __restrict__ eidx, int* __restrict__ tfs,
    float* __restrict__ out)
{
    int b = blockIdx.x >> 3, e = blockIdx.x & 7;
    int lane = threadIdx.x;
    const int* ip = eidx + (size_t)b * Nq;
    int base = (e * Bq + b) * CAPq;
    int cnt = 0;
    for (int it = 0; it < Nq / 64; ++it) {
        int n = it * 64 + lane;
        bool my = (ip[n] == e);
        unsigned long long mask = __ballot(my);
        if (my) {
            int pos = cnt + __popcll(mask & ((1ull << lane) - 1ull));
            if (pos < CAPq) {
                tfs[base + pos] = b * Nq + n;
            } else {
                // dropped token: output row must be zero (memset eliminated)
                float4 z = {0.f, 0.f, 0.f, 0.f};
                float4* op = (float4*)(out + (size_t)(b * Nq + n) * Dq);
                for (int q = 0; q < Dq / 4; ++q) op[q] = z;
            }
        }
        cnt += __popcll(mask);
    }
}

// ------------- dispatch: gather token rows -> bf16 expert buffers ----------
__global__ __launch_bounds__(128) void dispatch_kernel(
    const float* __restrict__ tok, const int* __restrict__ tfs,
    unsigned short* __restrict__ X)
{
    int r = blockIdx.x;          // 0 .. E*B*CAP-1
    int t = tfs[r];
    int d0 = threadIdx.x * 8;
    unsigned short o[8];
    if (t < 0) {
#pragma unroll
        for (int k = 0; k < 8; ++k) o[k] = 0;
    } else {
        const float4* p = (const float4*)(tok + (size_t)t * Dq + d0);
        float4 a = p[0], b = p[1];
        o[0]=f2bf(a.x); o[1]=f2bf(a.y); o[2]=f2bf(a.z); o[3]=f2bf(a.w);
        o[4]=f2bf(b.x); o[5]=f2bf(b.y); o[6]=f2bf(b.z); o[7]=f2bf(b.w);
    }
    *(uint4*)(X + (size_t)r * Dq + d0) = *(const uint4*)o;
}

// ------- weight transpose+convert: in [E][R][C] f32 -> out [E][C][R] bf16 --
__global__ __launch_bounds__(256) void transpose_cvt(
    const float* __restrict__ in, unsigned short* __restrict__ out,
    int R, int C)
{
    __shared__ float tile[32][33];
    int e = blockIdx.z;
    int c0 = blockIdx.x * 32, r0 = blockIdx.y * 32;
    int tx = threadIdx.x & 31, ty = threadIdx.x >> 5;
    const float* ip = in + (size_t)e * R * C;
#pragma unroll
    for (int rr = 0; rr < 4; ++rr)
        tile[ty + rr * 8][tx] = ip[(size_t)(r0 + ty + rr * 8) * C + c0 + tx];
    __syncthreads();
    unsigned short* op = out + (size_t)e * R * C;
#pragma unroll
    for (int rr = 0; rr < 4; ++rr)
        op[(size_t)(c0 + ty + rr * 8) * R + r0 + tx] = f2bf(tile[tx][ty + rr * 8]);
}

// ========== 8-phase 256x256 NT GEMM, BK=32, 2 blocks/CU ====================
// C[M][N] = A[M][K]*Bt[N][K]^T per expert. 512 thr = 8 waves (2M x 4N),
// per-wave 128x64. Halves = [128][32] bf16 (8KB), double-buffered by K-tile
// parity -> LDS 66KB -> 2 blocks/CU (cross-block phase stagger hides the
// per-phase lgkm/vmcnt waits). Counted vmcnt ledger (see derivation):
// steady body stages {R1.Bh0@0,Bh1@1,Ah1@2, N0.Ah0@3,Bh0@4,Bh1@5,Ah1@6,
// N1.Ah0@7}; vmcnt(3) at ends of ph0,1,3,4,5,7. Swizzle: chunk ^= row&3
// (<=2-way bank aliasing = free); pre-swizzled global src, linear LDS dest.
// MODE 0: H = relu(C) bf16.  MODE 1: scatter rows to Out with gate.
template <int MODE, int Ndim, int Kdim>
__global__ __launch_bounds__(512, 4) void g2cu(
    const unsigned short* __restrict__ A,   // [E][M][K] bf16
    const unsigned short* __restrict__ Bt,  // [E][N][K] bf16
    unsigned short* __restrict__ Hout,      // [E][M][N] bf16  (MODE 0)
    float* __restrict__ Out,                // [T][D] f32      (MODE 1)
    const int* __restrict__ tfs,            // [E][M]
    const float* __restrict__ gate)         // [T]
{
    constexpr int NKT = Kdim / 32;           // K-tiles (32-wide)
    constexpr int NI  = NKT / 2;             // bodies (2 K-tiles each)
    constexpr int NTB = Ndim / 256;
    constexpr int MT  = Mq / 256;            // 10
    constexpr int NWG = MT * NTB * Eq;       // multiple of 8

    __shared__ __align__(16) unsigned short As[2][2][128 * 32];  // 32 KiB
    __shared__ __align__(16) unsigned short Bs[2][2][128 * 32];  // 32 KiB
    __shared__ int   t_lds[256];
    __shared__ float g_lds[256];

    // XCD-aware bijective swizzle (NWG % 8 == 0)
    int flat = blockIdx.x;
    int wg = (flat & 7) * (NWG / 8) + (flat >> 3);
    int e   = wg / (MT * NTB);
    int rem = wg - e * (MT * NTB);
    int mb = rem / NTB, nb = rem - mb * NTB;
    int m0 = mb * 256, n0 = nb * 256;

    const char* Ae = (const char*)(A  + (size_t)e * Mq * Kdim + (size_t)m0 * Kdim);
    const char* Be = (const char*)(Bt + (size_t)e * Ndim * Kdim + (size_t)n0 * Kdim);

    const int tid = threadIdx.x;
    if (MODE == 1) {
        if (tid < 256) {
            int t = tfs[e * Mq + m0 + tid];
            t_lds[tid] = t;
            g_lds[tid] = (t >= 0) ? gate[t] : 0.f;
        }
        __syncthreads();   // publish + drain before staging ledger starts
    }

    const int lane = tid & 63;
    const int wv = tid >> 6;
    const int wr = wv & 1, wc = wv >> 1;     // 2M x 4N waves, per-wave 128x64
    const int lrow = lane & 15;
    const int lk = lane >> 4;                               // k-chunk 0..3
    const int cswz = ((lk ^ (lrow & 3)) << 4);              // read-side swizzle
    const int abase = (wr * 64 + lrow) * 64 + cswz;         // + mi<<13 + i*1024
    const int bbase = (wc * 32 + lrow) * 64 + cswz;         // + nj<<13 + j*1024

    // staging: half-tile [128][32] = 8KB = 512 thr x 16B, 1 gload each
    const size_t Kb = (size_t)Kdim * 2;                     // global row bytes
    const int sk = (((tid & 3) ^ ((tid >> 2) & 3)) << 4);   // pre-swizzled chunk
    const char* gA = Ae + (size_t)(tid >> 2) * Kb + sk;
    const char* gB = Be + (size_t)(tid >> 2) * Kb + sk;
    const int dst16 = tid * 16;

    #define STG_A(par, h, kt) gload_lds16(                                      \
        gA + (size_t)((h) * 128) * Kb + (size_t)(kt) * 64,                      \
        (char*)As + (((par) * 2 + (h)) << 13) + dst16)
    #define STG_B(par, h, kt) gload_lds16(                                      \
        gB + (size_t)((h) * 128) * Kb + (size_t)(kt) * 64,                      \
        (char*)Bs + (((par) * 2 + (h)) << 13) + dst16)

    bf16x8 aq[4], bq0[2], bq1[2];
    f32x4  acc[2][2][4][2] = {};     // [mi][nj][i][j]

    #define LDA(buf, mi) {                                                      \
        const char* _p = (const char*)As + (((buf) * 2 + (mi)) << 13) + abase;  \
        aq[0] = *(const bf16x8*)(_p);                                           \
        aq[1] = *(const bf16x8*)(_p + 1024);                                    \
        aq[2] = *(const bf16x8*)(_p + 2048);                                    \
        aq[3] = *(const bf16x8*)(_p + 3072); }
    #define LDB(bqz, buf, nj) {                                                 \
        const char* _p = (const char*)Bs + (((buf) * 2 + (nj)) << 13) + bbase;  \
        bqz[0] = *(const bf16x8*)(_p);                                          \
        bqz[1] = *(const bf16x8*)(_p + 1024); }

    #define MMQ(mi, bqz, z)                                                     \
        _Pragma("unroll")                                                       \
        for (int i = 0; i < 4; ++i)                                             \
        _Pragma("unroll")                                                       \
        for (int j = 0; j < 2; ++j)                                             \
            acc[mi][z][i][j] = __builtin_amdgcn_mfma_f32_16x16x32_bf16(         \
                aq[i], bqz[j], acc[mi][z][i][j], 0, 0, 0);

    #define SB __builtin_amdgcn_sched_barrier(0)
    #define BAR { __builtin_amdgcn_s_barrier(); SB; }
    #define LGKM0 { asm volatile("s_waitcnt lgkmcnt(0)"); SB; }
    #define VM(n) { asm volatile("s_waitcnt vmcnt(" #n ")"); SB; }
    #define P1 __builtin_amdgcn_s_setprio(1)
    #define P0 __builtin_amdgcn_s_setprio(0)

    // ---- prologue: tile0 (par0, 4 halves) + tile1.Ah0; invariant = 3 outst.
    STG_A(0, 0, 0);
    STG_B(0, 0, 0);
    STG_B(0, 1, 0);
    STG_A(0, 1, 0);
    STG_A(1, 0, 1);
    VM(3); BAR;                      // T0.Ah0 + T0.Bh0 resident

    for (int u = 0; u < NI - 1; ++u) {
        const int kt1 = 2 * u + 1, ktn0 = 2 * u + 2, ktn1 = 2 * u + 3;
        // ph0: reads p0(m0,n0); stage R1.Bh0
        LDA(0, 0); LDB(bq0, 0, 0);
        STG_B(1, 0, kt1);
        BAR; LGKM0; P1; MMQ(0, bq0, 0); P0; VM(3); BAR;
        // ph1: reads p0(n1); stage R1.Bh1
        LDB(bq1, 0, 1);
        STG_B(1, 1, kt1);
        BAR; LGKM0; P1; MMQ(0, bq1, 1); P0; VM(3); BAR;
        // ph2: reads p0(m1); stage R1.Ah1
        LDA(0, 1);
        STG_A(1, 1, kt1);
        BAR; LGKM0; P1; MMQ(1, bq0, 0); P0; BAR;
        // ph3: no reads; stage N0.Ah0
        STG_A(0, 0, ktn0);
        BAR; P1; MMQ(1, bq1, 1); P0; VM(3); BAR;
        // ph4: reads p1(m0,n0); stage N0.Bh0
        LDA(1, 0); LDB(bq0, 1, 0);
        STG_B(0, 0, ktn0);
        BAR; LGKM0; P1; MMQ(0, bq0, 0); P0; VM(3); BAR;
        // ph5: reads p1(n1); stage N0.Bh1
        LDB(bq1, 1, 1);
        STG_B(0, 1, ktn0);
        BAR; LGKM0; P1; MMQ(0, bq1, 1); P0; VM(3); BAR;
        // ph6: reads p1(m1); stage N0.Ah1
        LDA(1, 1);
        STG_A(0, 1, ktn0);
        BAR; LGKM0; P1; MMQ(1, bq0, 0); P0; BAR;
        // ph7: no reads; stage N1.Ah0
        STG_A(1, 0, ktn1);
        BAR; P1; MMQ(1, bq1, 1); P0; VM(3); BAR;
    }

    // ---- last body: stages only R1 halves at ph0,1,2; drain counts ----
    {
        const int kt1 = NKT - 1;
        // ph0
        LDA(0, 0); LDB(bq0, 0, 0);
        STG_B(1, 0, kt1);
        BAR; LGKM0; P1; MMQ(0, bq0, 0); P0; VM(3); BAR;
        // ph1
        LDB(bq1, 0, 1);
        STG_B(1, 1, kt1);
        BAR; LGKM0; P1; MMQ(0, bq1, 1); P0; VM(3); BAR;
        // ph2
        LDA(0, 1);
        STG_A(1, 1, kt1);
        BAR; LGKM0; P1; MMQ(1, bq0, 0); P0; BAR;
        // ph3 (no stage): retire R1.Ah0,Bh0 -> 2 left
        BAR; P1; MMQ(1, bq1, 1); P0; VM(2); BAR;
        // ph4: retire R1.Bh1
        LDA(1, 0); LDB(bq0, 1, 0);
        BAR; LGKM0; P1; MMQ(0, bq0, 0); P0; VM(1); BAR;
        // ph5: retire R1.Ah1
        LDB(bq1, 1, 1);
        BAR; LGKM0; P1; MMQ(0, bq1, 1); P0; VM(0); BAR;
        // ph6
        LDA(1, 1);
        BAR; LGKM0; P1; MMQ(1, bq0, 0); P0; BAR;
        // ph7
        P1; MMQ(1, bq1, 1); P0;
    }

    // -------------------------------- epilogue --------------------------------
    if (MODE == 0) {
        unsigned short* Hp = Hout + (size_t)e * Mq * Ndim;
#pragma unroll
        for (int mi = 0; mi < 2; ++mi)
#pragma unroll
        for (int nj = 0; nj < 2; ++nj)
#pragma unroll
        for (int i = 0; i < 4; ++i) {
            int row = m0 + mi * 128 + wr * 64 + i * 16 + lk * 4;
#pragma unroll
            for (int j = 0; j < 2; ++j) {
                int col = n0 + nj * 128 + wc * 32 + j * 16 + lrow;
#pragma unroll
                for (int r = 0; r < 4; ++r)
                    Hp[(size_t)(row + r) * Ndim + col] =
                        f2bf(fmaxf(acc[mi][nj][i][j][r], 0.f));
            }
        }
    } else {
#pragma unroll
        for (int mi = 0; mi < 2; ++mi)
#pragma unroll
        for (int i = 0; i < 4; ++i) {
            int rl = mi * 128 + wr * 64 + i * 16 + lk * 4;
#pragma unroll
            for (int r = 0; r < 4; ++r) {
                int tt = t_lds[rl + r];
                if (tt < 0) continue;
                float g = g_lds[rl + r];
#pragma unroll
                for (int nj = 0; nj < 2; ++nj)
#pragma unroll
                for (int j = 0; j < 2; ++j) {
                    int col = n0 + nj * 128 + wc * 32 + j * 16 + lrow;
                    Out[(size_t)tt * Dq + col] = g * acc[mi][nj][i][j][r];
                }
            }
        }
    }
    #undef STG_A
    #undef STG_B
    #undef LDA
    #undef LDB
    #undef MMQ
    #undef SB
    #undef BAR
    #undef LGKM0
    #undef VM
    #undef P1
    #undef P0
}

// ---------------------------------------------------------------------------
extern "C" void kernel_launch(void* const* d_in, const int* in_sizes, int n_in,
                              void* d_out, int out_size, void* d_ws, size_t ws_size,
                              hipStream_t stream)
{
    const float* tok = (const float*)d_in[0];
    const float* Wg  = (const float*)d_in[1];
    const float* W1  = (const float*)d_in[2];
    const float* W2  = (const float*)d_in[3];
    float* out = (float*)d_out;
    char* ws = (char*)d_ws;

    // workspace layout (bytes)
    unsigned short* W1T = (unsigned short*)(ws);                    // [E][DFF][D] bf16  67108864
    unsigned short* W2T = (unsigned short*)(ws + 67108864);         // [E][D][DFF] bf16  67108864
    unsigned short* X   = (unsigned short*)(ws + 134217728);        // [E][M][D]  bf16   41943040
    unsigned short* H   = (unsigned short*)(ws + 176160768);        // [E][M][DFF] bf16 167772160
    int*   tfs  = (int*)(ws + 343932928);                           // [E][M]            81920
    int*   eidx = (int*)(ws + 344014848);                           // [T]               65536
    float* gate = (float*)(ws + 344080384);                         // [T]               65536

    hipMemsetAsync(tfs, 0xFF, Eq * Mq * 4, stream);

    route_kernel<<<Tq / 4, 256, 0, stream>>>(tok, Wg, eidx, gate);
    slot_kernel<<<Bq * Eq, 64, 0, stream>>>(eidx, tfs, out);
    dispatch_kernel<<<Eq * Mq, 128, 0, stream>>>(tok, tfs, X);
    transpose_cvt<<<dim3(DFFq / 32, Dq / 32, Eq), 256, 0, stream>>>(W1, W1T, Dq, DFFq);
    transpose_cvt<<<dim3(Dq / 32, DFFq / 32, Eq), 256, 0, stream>>>(W2, W2T, DFFq, Dq);

    // GEMM1: H = relu(X @ W1): 10 x 16 x 8 = 1280 blocks @ 2/CU
    g2cu<0, DFFq, Dq><<<(Mq / 256) * (DFFq / 256) * Eq, 512, 0, stream>>>(
        X, W1T, H, nullptr, nullptr, nullptr);
    // GEMM2: out[token] = gate * (H @ W2): 10 x 4 x 8 = 320 blocks @ 2/CU
    g2cu<1, Dq, DFFq><<<(Mq / 256) * (Dq / 256) * Eq, 512, 0, stream>>>(
        H, W2T, nullptr, out, tfs, gate);
}

// Round 7
// 561.728 us; speedup vs baseline: 6.8323x; 6.8323x over previous
//
#include <hip/hip_runtime.h>

// MoE switch layer: B=8, N=2048, D=1024, E=8, DFF=4096, CAP=320
#define Bq 8
#define Nq 2048
#define Dq 1024
#define Eq 8
#define DFFq 4096
#define CAPq 320
#define Mq (Bq * CAPq)   // 2560 rows per expert
#define Tq (Bq * Nq)     // 16384 tokens

typedef __attribute__((ext_vector_type(8))) short bf16x8;
typedef __attribute__((ext_vector_type(4))) float f32x4;

static __device__ __forceinline__ unsigned short f2bf(float f) {
    union { float f; unsigned u; } v;
    v.f = f;
    unsigned r = v.u + 0x7fffu + ((v.u >> 16) & 1u);   // RNE
    return (unsigned short)(r >> 16);
}

static __device__ __forceinline__ void gload_lds16(const void* g, void* l) {
    __builtin_amdgcn_global_load_lds(
        (const __attribute__((address_space(1))) unsigned int*)g,
        (__attribute__((address_space(3))) unsigned int*)l, 16, 0, 0);
}

// ---------------- routing: logits -> softmax -> argmax/gate ----------------
__global__ __launch_bounds__(256) void route_kernel(
    const float* __restrict__ tok, const float* __restrict__ Wg,
    int* __restrict__ eidx, float* __restrict__ gate)
{
    int wv = threadIdx.x >> 6, lane = threadIdx.x & 63;
    int t = blockIdx.x * 4 + wv;
    const float* tp = tok + (size_t)t * Dq;
    float acc[8] = {0.f,0.f,0.f,0.f,0.f,0.f,0.f,0.f};
    for (int it = 0; it < Dq / 64; ++it) {
        int d = it * 64 + lane;
        float x = tp[d];
        const float4* w = (const float4*)(Wg + (size_t)d * 8);
        float4 w0 = w[0], w1 = w[1];
        acc[0] += x * w0.x; acc[1] += x * w0.y; acc[2] += x * w0.z; acc[3] += x * w0.w;
        acc[4] += x * w1.x; acc[5] += x * w1.y; acc[6] += x * w1.z; acc[7] += x * w1.w;
    }
#pragma unroll
    for (int e = 0; e < 8; ++e)
#pragma unroll
        for (int off = 32; off; off >>= 1)
            acc[e] += __shfl_xor(acc[e], off, 64);
    if (lane == 0) {
        float m = acc[0]; int bi = 0;
#pragma unroll
        for (int e = 1; e < 8; ++e) if (acc[e] > m) { m = acc[e]; bi = e; }
        float s = 0.f;
#pragma unroll
        for (int e = 0; e < 8; ++e) s += expf(acc[e] - m);
        eidx[t] = bi;
        gate[t] = 1.0f / s;   // max prob
    }
}

// ------------- slot assignment + zero dropped-token output rows ------------
__global__ __launch_bounds__(64) void slot_kernel(
    const int* __restrict__ eidx, int* __restrict__ tfs,
    float* __restrict__ out)
{
    int b = blockIdx.x >> 3, e = blockIdx.x & 7;
    int lane = threadIdx.x;
    const int* ip = eidx + (size_t)b * Nq;
    int base = (e * Bq + b) * CAPq;
    int cnt = 0;
    for (int it = 0; it < Nq / 64; ++it) {
        int n = it * 64 + lane;
        bool my = (ip[n] == e);
        unsigned long long mask = __ballot(my);
        if (my) {
            int pos = cnt + __popcll(mask & ((1ull << lane) - 1ull));
            if (pos < CAPq) {
                tfs[base + pos] = b * Nq + n;
            } else {
                // dropped token: its output row must be zero
                float4 z = {0.f, 0.f, 0.f, 0.f};
                float4* op = (float4*)(out + (size_t)(b * Nq + n) * Dq);
                for (int q = 0; q < Dq / 4; ++q) op[q] = z;
            }
        }
        cnt += __popcll(mask);
    }
}

// ------------- dispatch: gather token rows -> bf16 expert buffers ----------
__global__ __launch_bounds__(128) void dispatch_kernel(
    const float* __restrict__ tok, const int* __restrict__ tfs,
    unsigned short* __restrict__ X)
{
    int r = blockIdx.x;          // 0 .. E*B*CAP-1
    int t = tfs[r];
    int d0 = threadIdx.x * 8;
    unsigned short o[8];
    if (t < 0) {
#pragma unroll
        for (int k = 0; k < 8; ++k) o[k] = 0;
    } else {
        const float4* p = (const float4*)(tok + (size_t)t * Dq + d0);
        float4 a = p[0], b = p[1];
        o[0]=f2bf(a.x); o[1]=f2bf(a.y); o[2]=f2bf(a.z); o[3]=f2bf(a.w);
        o[4]=f2bf(b.x); o[5]=f2bf(b.y); o[6]=f2bf(b.z); o[7]=f2bf(b.w);
    }
    *(uint4*)(X + (size_t)r * Dq + d0) = *(const uint4*)o;
}

// ------- weight transpose+convert: in [E][R][C] f32 -> out [E][C][R] bf16 --
__global__ __launch_bounds__(256) void transpose_cvt(
    const float* __restrict__ in, unsigned short* __restrict__ out,
    int R, int C)
{
    __shared__ float tile[32][33];
    int e = blockIdx.z;
    int c0 = blockIdx.x * 32, r0 = blockIdx.y * 32;
    int tx = threadIdx.x & 31, ty = threadIdx.x >> 5;
    const float* ip = in + (size_t)e * R * C;
#pragma unroll
    for (int rr = 0; rr < 4; ++rr)
        tile[ty + rr * 8][tx] = ip[(size_t)(r0 + ty + rr * 8) * C + c0 + tx];
    __syncthreads();
    unsigned short* op = out + (size_t)e * R * C;
#pragma unroll
    for (int rr = 0; rr < 4; ++rr)
        op[(size_t)(c0 + ty + rr * 8) * R + r0 + tx] = f2bf(tile[tx][ty + rr * 8]);
}

// ===== 8-phase 256x256 NT GEMM, deep-prefetch counted-vmcnt schedule =======
// C[M][N] = A[M][K]*Bt[N][K]^T per expert. BM=BN=256, BK=64, 512 thr
// (8 waves = 2M x 4N, per-wave 128x64). LDS: 2 parity buffers x 2 halves per
// operand ([128][64] bf16 = 16KB each) = 128 KiB.
// Stage order (1 half-tile = 2 gload_lds16/thread per phase), derived so each
// half is staged 5-6 phases before its first read and >=1 barrier after the
// last read of its old content (WAR-safe):
//   ph0: par1.B.h1(kt1)  ph1: par1.A.h1(kt1)  ph2: par0.A.h0(kt0+2)
//   ph3: par0.B.h0       ph4: par0.B.h1       ph5: par0.A.h1
//   ph6: par1.A.h0(kt1+2) ph7: par1.B.h0(kt1+2)
// Waits: vmcnt(8) at ph3/ph4/ph5-ends, vmcnt(4) at ph7-end (ledger verified:
// entering-iter outstanding = 4 loads = next kt1's A.h0/B.h0).
// MODE 0: H = relu(C) bf16.  MODE 1: scatter rows to Out with gate.
template <int MODE, int Ndim, int Kdim>
__global__ __launch_bounds__(512, 2) void gemm8p(
    const unsigned short* __restrict__ A,   // [E][M][K] bf16
    const unsigned short* __restrict__ Bt,  // [E][N][K] bf16
    unsigned short* __restrict__ Hout,      // [E][M][N] bf16  (MODE 0)
    float* __restrict__ Out,                // [T][D] f32      (MODE 1)
    const int* __restrict__ tfs,            // [E][M]
    const float* __restrict__ gate)         // [T]
{
    constexpr int NKT = Kdim / 64;           // K-tiles
    constexpr int NI  = NKT / 2;             // iterations (2 K-tiles each)
    constexpr int NTB = Ndim / 256;
    constexpr int MT  = Mq / 256;            // 10
    constexpr int NWG = MT * NTB * Eq;       // multiple of 8

    __shared__ __align__(16) unsigned short As[2 * 2 * 128 * 64];  // 64 KiB
    __shared__ __align__(16) unsigned short Bs[2 * 2 * 128 * 64];  // 64 KiB
    __shared__ int   t_lds[256];
    __shared__ float g_lds[256];

    // XCD-aware bijective swizzle (NWG % 8 == 0)
    int flat = blockIdx.x;
    int wg = (flat & 7) * (NWG / 8) + (flat >> 3);
    int e   = wg / (MT * NTB);
    int rem = wg - e * (MT * NTB);
    int mb = rem / NTB, nb = rem - mb * NTB;
    int m0 = mb * 256, n0 = nb * 256;

    const char* Ae = (const char*)(A  + (size_t)e * Mq * Kdim + (size_t)m0 * Kdim);
    const char* Be = (const char*)(Bt + (size_t)e * Ndim * Kdim + (size_t)n0 * Kdim);

    const int tid = threadIdx.x;
    if (MODE == 1) {
        if (tid < 256) {
            int t = tfs[e * Mq + m0 + tid];
            t_lds[tid] = t;
            g_lds[tid] = (t >= 0) ? gate[t] : 0.f;
        }
        __syncthreads();   // publish + drain before the staging ledger starts
    }

    const int lane = tid & 63;
    const int wv = tid >> 6;
    const int wr = wv & 1, wc = wv >> 1;     // 2M x 4N waves
    const int lrow = lane & 15;
    const int lk = lane >> 4;
    const int swz = (lane & 7) << 4;

    // staging: per half-tile (128 rows x 64 cols bf16) = 2 gload_lds16/thread
    const int sk = ((tid & 7) << 4) ^ (((tid >> 3) & 7) << 4);   // pre-swizzled src
    const size_t Kb = (size_t)Kdim * 2;                           // row bytes
    const char* gA = Ae + (size_t)(tid >> 3) * Kb + sk;
    const char* gB = Be + (size_t)(tid >> 3) * Kb + sk;
    const int ldst = wv << 10;                                    // wave-uniform

    #define STG_A(par, h, kt) {                                                 \
        const char* _g = gA + (size_t)((h) * 128) * Kb + (size_t)(kt) * 128;    \
        char* _l = (char*)As + (((par) * 2 + (h)) * 16384) + ldst;              \
        gload_lds16(_g,                   _l);                                  \
        gload_lds16(_g + (size_t)64 * Kb, _l + 8192); }
    #define STG_B(par, h, kt) {                                                 \
        const char* _g = gB + (size_t)((h) * 128) * Kb + (size_t)(kt) * 128;    \
        char* _l = (char*)Bs + (((par) * 2 + (h)) * 16384) + ldst;              \
        gload_lds16(_g,                   _l);                                  \
        gload_lds16(_g + (size_t)64 * Kb, _l + 8192); }

    bf16x8 aq[4][2];                 // A frags (time-shared across mi phases)
    bf16x8 bq0[2][2], bq1[2][2];     // B frags, two sets
    f32x4  acc[2][2][4][2] = {};     // [mi][nj][i][j]

    #define LDA(par, mi) {                                                      \
        const char* _p = (const char*)As + (((par) * 2 + (mi)) * 16384);        \
        _Pragma("unroll")                                                       \
        for (int i = 0; i < 4; ++i) {                                           \
            int rh = wr * 64 + i * 16 + lrow;                                   \
            aq[i][0] = *(const bf16x8*)(_p + rh * 128 + ((lk * 16) ^ swz));     \
            aq[i][1] = *(const bf16x8*)(_p + rh * 128 + ((64 + lk * 16) ^ swz)); } }

    #define LDB(bqz, par, nj) {                                                 \
        const char* _p = (const char*)Bs + (((par) * 2 + (nj)) * 16384);        \
        _Pragma("unroll")                                                       \
        for (int j = 0; j < 2; ++j) {                                           \
            int rh = wc * 32 + j * 16 + lrow;                                   \
            bqz[j][0] = *(const bf16x8*)(_p + rh * 128 + ((lk * 16) ^ swz));    \
            bqz[j][1] = *(const bf16x8*)(_p + rh * 128 + ((64 + lk * 16) ^ swz)); } }

    #define MMQ(mi, bqz, z)                                                     \
        _Pragma("unroll")                                                       \
        for (int i = 0; i < 4; ++i)                                             \
        _Pragma("unroll")                                                       \
        for (int j = 0; j < 2; ++j)                                             \
        _Pragma("unroll")                                                       \
        for (int kk = 0; kk < 2; ++kk)                                          \
            acc[mi][z][i][j] = __builtin_amdgcn_mfma_f32_16x16x32_bf16(         \
                aq[i][kk], bqz[j][kk], acc[mi][z][i][j], 0, 0, 0);

    #define SB __builtin_amdgcn_sched_barrier(0)
    #define BAR { __builtin_amdgcn_s_barrier(); SB; }
    #define LGKM0 { asm volatile("s_waitcnt lgkmcnt(0)"); SB; }
    #define VM(n) { asm volatile("s_waitcnt vmcnt(" #n ")"); SB; }
    #define P1 __builtin_amdgcn_s_setprio(1)
    #define P0 __builtin_amdgcn_s_setprio(0)

    // ---- prologue: par0 <- kt0 (4 halves), par1.A.h0/B.h0 <- kt1 ----
    STG_A(0, 0, 0);
    STG_B(0, 0, 0);
    STG_B(0, 1, 0);
    STG_A(0, 1, 0);
    STG_A(1, 0, 1);
    STG_B(1, 0, 1);
    VM(4); BAR;          // par0(kt0) resident; outstanding = 4 (par1.A0,B0)

    for (int u = 0; u < NI - 1; ++u) {
        const int kt1 = 2 * u + 1, ktn0 = 2 * u + 2, ktn1 = 2 * u + 3;
        // ph0: reads par0(A.h0 + B.h0); stage par1.B.h1(kt1)
        LDA(0, 0); LDB(bq0, 0, 0);
        STG_B(1, 1, kt1);
        BAR; LGKM0; P1; MMQ(0, bq0, 0); P0; BAR;
        // ph1: reads par0.B.h1; stage par1.A.h1(kt1)
        LDB(bq1, 0, 1);
        STG_A(1, 1, kt1);
        BAR; LGKM0; P1; MMQ(0, bq1, 1); P0; BAR;
        // ph2: reads par0.A.h1; stage par0.A.h0(kt0+2)
        LDA(0, 1);
        STG_A(0, 0, ktn0);
        BAR; LGKM0; P1; MMQ(1, bq0, 0); P0; BAR;
        // ph3: no reads; stage par0.B.h0(kt0+2); retire par1.A.h0/B.h0(kt1)
        STG_B(0, 0, ktn0);
        BAR; P1; MMQ(1, bq1, 1); P0; VM(8); BAR;
        // ph4: reads par1(A.h0 + B.h0); stage par0.B.h1(kt0+2); retire par1.B.h1
        LDA(1, 0); LDB(bq0, 1, 0);
        STG_B(0, 1, ktn0);
        BAR; LGKM0; P1; MMQ(0, bq0, 0); P0; VM(8); BAR;
        // ph5: reads par1.B.h1; stage par0.A.h1(kt0+2); retire par1.A.h1
        LDB(bq1, 1, 1);
        STG_A(0, 1, ktn0);
        BAR; LGKM0; P1; MMQ(0, bq1, 1); P0; VM(8); BAR;
        // ph6: reads par1.A.h1; stage par1.A.h0(kt1+2)
        LDA(1, 1);
        STG_A(1, 0, ktn1);
        BAR; LGKM0; P1; MMQ(1, bq0, 0); P0; BAR;
        // ph7: no reads; stage par1.B.h0(kt1+2); retire all par0(kt0+2)
        STG_B(1, 0, ktn1);
        BAR; P1; MMQ(1, bq1, 1); P0; VM(4); BAR;
    }

    // ---- last body (no kt+2 staging; drain counts) ----
    {
        const int kt1 = NKT - 1;
        // ph0
        LDA(0, 0); LDB(bq0, 0, 0);
        STG_B(1, 1, kt1);
        BAR; LGKM0; P1; MMQ(0, bq0, 0); P0; BAR;
        // ph1
        LDB(bq1, 0, 1);
        STG_A(1, 1, kt1);
        BAR; LGKM0; P1; MMQ(0, bq1, 1); P0; BAR;
        // ph2
        LDA(0, 1);
        BAR; LGKM0; P1; MMQ(1, bq0, 0); P0; BAR;
        // ph3: retire par1.A.h0/B.h0 (outstanding: 4 carried + ph0,ph1 = 8)
        BAR; P1; MMQ(1, bq1, 1); P0; VM(4); BAR;
        // ph4: retire par1.B.h1 (ph0's stage)
        LDA(1, 0); LDB(bq0, 1, 0);
        BAR; LGKM0; P1; MMQ(0, bq0, 0); P0; VM(2); BAR;
        // ph5: retire par1.A.h1 (ph1's stage)
        LDB(bq1, 1, 1);
        BAR; LGKM0; P1; MMQ(0, bq1, 1); P0; VM(0); BAR;
        // ph6
        LDA(1, 1);
        BAR; LGKM0; P1; MMQ(1, bq0, 0); P0; BAR;
        // ph7
        P1; MMQ(1, bq1, 1); P0;
    }

    // -------------------------------- epilogue --------------------------------
    if (MODE == 0) {
        unsigned short* Hp = Hout + (size_t)e * Mq * Ndim;
#pragma unroll
        for (int mi = 0; mi < 2; ++mi)
#pragma unroll
        for (int nj = 0; nj < 2; ++nj)
#pragma unroll
        for (int i = 0; i < 4; ++i) {
            int row = m0 + mi * 128 + wr * 64 + i * 16 + lk * 4;
#pragma unroll
            for (int j = 0; j < 2; ++j) {
                int col = n0 + nj * 128 + wc * 32 + j * 16 + lrow;
#pragma unroll
                for (int r = 0; r < 4; ++r)
                    Hp[(size_t)(row + r) * Ndim + col] =
                        f2bf(fmaxf(acc[mi][nj][i][j][r], 0.f));
            }
        }
    } else {
#pragma unroll
        for (int mi = 0; mi < 2; ++mi)
#pragma unroll
        for (int i = 0; i < 4; ++i) {
            int rl = mi * 128 + wr * 64 + i * 16 + lk * 4;
#pragma unroll
            for (int r = 0; r < 4; ++r) {
                int tt = t_lds[rl + r];
                if (tt < 0) continue;
                float g = g_lds[rl + r];
#pragma unroll
                for (int nj = 0; nj < 2; ++nj)
#pragma unroll
                for (int j = 0; j < 2; ++j) {
                    int col = n0 + nj * 128 + wc * 32 + j * 16 + lrow;
                    Out[(size_t)tt * Dq + col] = g * acc[mi][nj][i][j][r];
                }
            }
        }
    }
    #undef STG_A
    #undef STG_B
    #undef LDA
    #undef LDB
    #undef MMQ
    #undef SB
    #undef BAR
    #undef LGKM0
    #undef VM
    #undef P1
    #undef P0
}

// ---------------------------------------------------------------------------
extern "C" void kernel_launch(void* const* d_in, const int* in_sizes, int n_in,
                              void* d_out, int out_size, void* d_ws, size_t ws_size,
                              hipStream_t stream)
{
    const float* tok = (const float*)d_in[0];
    const float* Wg  = (const float*)d_in[1];
    const float* W1  = (const float*)d_in[2];
    const float* W2  = (const float*)d_in[3];
    float* out = (float*)d_out;
    char* ws = (char*)d_ws;

    // workspace layout (bytes)
    unsigned short* W1T = (unsigned short*)(ws);                    // [E][DFF][D] bf16  67108864
    unsigned short* W2T = (unsigned short*)(ws + 67108864);         // [E][D][DFF] bf16  67108864
    unsigned short* X   = (unsigned short*)(ws + 134217728);        // [E][M][D]  bf16   41943040
    unsigned short* H   = (unsigned short*)(ws + 176160768);        // [E][M][DFF] bf16 167772160
    int*   tfs  = (int*)(ws + 343932928);                           // [E][M]            81920
    int*   eidx = (int*)(ws + 344014848);                           // [T]               65536
    float* gate = (float*)(ws + 344080384);                         // [T]               65536

    hipMemsetAsync(tfs, 0xFF, Eq * Mq * 4, stream);

    route_kernel<<<Tq / 4, 256, 0, stream>>>(tok, Wg, eidx, gate);
    slot_kernel<<<Bq * Eq, 64, 0, stream>>>(eidx, tfs, out);
    dispatch_kernel<<<Eq * Mq, 128, 0, stream>>>(tok, tfs, X);
    transpose_cvt<<<dim3(DFFq / 32, Dq / 32, Eq), 256, 0, stream>>>(W1, W1T, Dq, DFFq);
    transpose_cvt<<<dim3(Dq / 32, DFFq / 32, Eq), 256, 0, stream>>>(W2, W2T, DFFq, Dq);

    // GEMM1: H = relu(X @ W1): 10 x 16 x 8 = 1280 blocks = 5 exact rounds
    gemm8p<0, DFFq, Dq><<<(Mq / 256) * (DFFq / 256) * Eq, 512, 0, stream>>>(
        X, W1T, H, nullptr, nullptr, nullptr);
    // GEMM2: out[token] = gate * (H @ W2): 10 x 4 x 8 = 320 blocks
    gemm8p<1, Dq, DFFq><<<(Mq / 256) * (Dq / 256) * Eq, 512, 0, stream>>>(
        H, W2T, nullptr, out, tfs, gate);
}